// Round 7
// baseline (31.612 us; speedup 1.0000x reference)
//
#include <hip/hip_runtime.h>
#include <math.h>

#define LOG2E 1.4426950408889634f
#define LN2   0.6931471805599453f

// 13 VALU inst, 3 hardware trans (2x v_exp_f32, 1x v_log_f32).
// Identity: B = max(s,0)+log1p(exp(-|x|)) with s = t ? -x : x  is BOTH the
// stable BCE-with-logits AND -log(pt). pt = exp(-B).
// combined = 0.5*B*(1 + 0.25*(1-pt)^2); w carries 0.5 and temporal reweight.
__device__ __forceinline__ float elem_loss(float x, int t, float w) {
    const float s  = t ? -x : x;
    const float e  = __builtin_amdgcn_exp2f(fabsf(x) * -LOG2E);   // exp(-|x|)
    const float L  = LN2 * __builtin_amdgcn_logf(1.0f + e);       // log1p(e)
    const float B  = fmaxf(s, 0.0f) + L;                          // bce == -log(pt)
    const float pt = __builtin_amdgcn_exp2f(B * -LOG2E);
    const float om = 1.0f - pt;
    return (w * B) * __builtin_fmaf(0.25f * om, om, 1.0f);
}

__global__ __launch_bounds__(256) void loss_partial_kernel(
        const float* __restrict__ x, const int* __restrict__ tg,
        float* __restrict__ partial, int n4, int n) {
    const int tid    = blockIdx.x * blockDim.x + threadIdx.x;
    const int stride = gridDim.x * blockDim.x;
    const int lane   = threadIdx.x & 63;
    float sum = 0.0f;

    const float4* x4 = reinterpret_cast<const float4*>(x);
    const int4*   t4 = reinterpret_cast<const int4*>(tg);

    // UNIT-STRIDE layout: lane i owns float4[g], g = tid + k*stride.
    // Each wave-load is one contiguous 1 KB block (8 full 128B lines,
    // each line consumed exactly once), vs the 32B-strided pattern of
    // previous rounds where every line was half-consumed by 2 loads.
    for (int g = tid; g < n4; g += stride) {
        const float4 xv = x4[g];
        const int4   tv = t4[g];

        // pack this group's 4 target bits: bit j = targets[4g+j]
        const int b = tv.x | (tv.y << 1) | (tv.z << 2) | (tv.w << 3);

        // neighbors hold the preceding groups (consecutive lanes = consecutive g)
        int p1 = __shfl_up(b, 1);          // group g-1 bits (lanes >= 1)
        int p2 = __shfl_up(b, 2);          // group g-2 bits (lanes >= 2)
        if (lane < 2) {                    // wave-edge fallback, 2/64 lanes
            p2 = (g >= 2) ? (tg[4 * g - 5] << 3) : 0;   // only bit 3 is used
            if (lane == 0) {
                p1 = 0;
                if (g >= 1) {
                    const int4 pv = t4[g - 1];           // L2-hit
                    p1 = pv.x | (pv.y << 1) | (pv.z << 2) | (pv.w << 3);
                }
            }
        }
        // W bit layout: bit0 = targets[4g-5], bits1-4 = targets[4g-4..4g-1],
        // bits5-8 = targets[4g..4g+3]. Element j's 5-wide causal window is
        // W bits [j .. j+4].
        const int W = ((p2 >> 3) & 1) | (p1 << 1) | (b << 5);

        float s4 = 0.0f;
        #pragma unroll
        for (int j = 0; j < 4; ++j) {
            const float xe  = ((const float*)&xv)[j];
            const int   t   = (b >> j) & 1;
            const int   hit = t & (((W >> j) & 31) ? 1 : 0);
            s4 += elem_loss(xe, t, hit ? 0.4f : 0.5f);
        }
        sum += s4;
    }

    // scalar tail for n not divisible by 4
    for (int g = 4 * n4 + tid; g < n; g += stride) {
        const int t = tg[g];
        int any = 0;
        #pragma unroll
        for (int k = 1; k <= 5; ++k) if (g - k >= 0) any |= tg[g - k];
        sum += elem_loss(x[g], t, (t & (any ? 1 : 0)) ? 0.4f : 0.5f);
    }

    // wave (64-lane) shfl reduction, then LDS across 4 waves
    #pragma unroll
    for (int off = 32; off > 0; off >>= 1) sum += __shfl_down(sum, off);
    __shared__ float wsum[4];
    const int wid = threadIdx.x >> 6;
    if (lane == 0) wsum[wid] = sum;
    __syncthreads();
    if (threadIdx.x == 0)
        partial[blockIdx.x] = (wsum[0] + wsum[1]) + (wsum[2] + wsum[3]);
}

__global__ __launch_bounds__(256) void final_reduce_kernel(
        const float* __restrict__ partial, int nb,
        float* __restrict__ out, float invN) {
    float s = 0.0f;
    for (int i = threadIdx.x; i < nb; i += 256) s += partial[i];
    #pragma unroll
    for (int off = 32; off > 0; off >>= 1) s += __shfl_down(s, off);
    __shared__ float wsum[4];
    const int lane = threadIdx.x & 63;
    const int wid  = threadIdx.x >> 6;
    if (lane == 0) wsum[wid] = s;
    __syncthreads();
    if (threadIdx.x == 0)
        out[0] = ((wsum[0] + wsum[1]) + (wsum[2] + wsum[3])) * invN;
}

extern "C" void kernel_launch(void* const* d_in, const int* in_sizes, int n_in,
                              void* d_out, int out_size, void* d_ws, size_t ws_size,
                              hipStream_t stream) {
    const float* x  = (const float*)d_in[0];
    const int*   tg = (const int*)d_in[1];
    float* out      = (float*)d_out;
    float* partial  = (float*)d_ws;

    const int n  = in_sizes[0];
    const int n4 = n / 4;
    const int NB = 2048;   // 8 wg/CU = 32 waves/CU; grid-stride the rest

    loss_partial_kernel<<<NB, 256, 0, stream>>>(x, tg, partial, n4, n);
    final_reduce_kernel<<<1, 256, 0, stream>>>(partial, NB, out, 1.0f / (float)n);
}

// Round 9
// 30.376 us; speedup vs baseline: 1.0407x; 1.0407x over previous
//
#include <hip/hip_runtime.h>
#include <math.h>

#define LOG2E 1.4426950408889634f
#define LN2   0.6931471805599453f

typedef float __attribute__((ext_vector_type(4))) fx4;   // clang vector: valid
                                                         // for nontemporal builtins

// 13 VALU inst, 3 hardware trans (2x v_exp_f32, 1x v_log_f32).
// Identity: B = max(s,0)+log1p(exp(-|x|)) with s = t ? -x : x  is BOTH the
// stable BCE-with-logits AND -log(pt). pt = exp(-B).
// combined = 0.5*B*(1 + 0.25*(1-pt)^2); w carries 0.5 and temporal reweight.
__device__ __forceinline__ float elem_loss(float x, int t, float w) {
    const float s  = t ? -x : x;
    const float e  = __builtin_amdgcn_exp2f(fabsf(x) * -LOG2E);   // exp(-|x|)
    const float L  = LN2 * __builtin_amdgcn_logf(1.0f + e);       // log1p(e)
    const float B  = fmaxf(s, 0.0f) + L;                          // bce == -log(pt)
    const float pt = __builtin_amdgcn_exp2f(B * -LOG2E);
    const float om = 1.0f - pt;
    return (w * B) * __builtin_fmaf(0.25f * om, om, 1.0f);
}

__global__ __launch_bounds__(256) void loss_partial_kernel(
        const float* __restrict__ x, const int* __restrict__ tg,
        float* __restrict__ partial, int n8, int n) {
    const int tid    = blockIdx.x * blockDim.x + threadIdx.x;
    const int stride = gridDim.x * blockDim.x;
    float sum = 0.0f;

    const fx4*  x4 = reinterpret_cast<const fx4*>(x);
    const int4* t4 = reinterpret_cast<const int4*>(tg);

    for (int i = tid; i < n8; i += stride) {
        // x stream: NONTEMPORAL (nt flag) -> lowest L3 replacement priority.
        // x is 64 MB read-once-per-replay; keeping it OUT of L3 lets the
        // targets stream (64 MB) stay fully L3-resident across graph replays
        // instead of the two streams thrashing each other out (observed:
        // FETCH_SIZE ~66 MB = half the 128 MiB working set re-fetched).
        const fx4  xa = __builtin_nontemporal_load(&x4[2 * i]);
        const fx4  xb = __builtin_nontemporal_load(&x4[2 * i + 1]);
        const int4 ta = t4[2 * i];
        const int4 tb = t4[2 * i + 1];

        int P1 = 0, P2 = 0, P3 = 0, P4 = 0, P5 = 0;  // tg[8i-1..8i-5]
        if (i > 0) {
            const int4 pv = t4[2 * i - 1];
            P1 = pv.w; P2 = pv.z; P3 = pv.y; P4 = pv.x;
            P5 = tg[8 * i - 5];                       // L1/L2 hit
        }

        // prefix-ORs for the 5-wide causal window (targets are 0/1)
        const int q2 = P1 | P2, q3 = q2 | P3, q4 = q3 | P4;
        const int s1 = ta.x | ta.y, s2 = s1 | ta.z, s3 = s2 | ta.w;
        const int w0 = q4 | P5;
        const int w1 = ta.x | q4;
        const int w2 = s1 | q3;
        const int w3 = s2 | q2;
        const int w4 = s3 | P1;
        const int w5 = tb.x | s3;
        const int w6 = tb.y | tb.x | ta.w | ta.z | ta.y;
        const int w7 = tb.z | tb.y | tb.x | ta.w | ta.z;

        const float c0 = elem_loss(xa.x, ta.x, (ta.x & w0) ? 0.4f : 0.5f);
        const float c1 = elem_loss(xa.y, ta.y, (ta.y & w1) ? 0.4f : 0.5f);
        const float c2 = elem_loss(xa.z, ta.z, (ta.z & w2) ? 0.4f : 0.5f);
        const float c3 = elem_loss(xa.w, ta.w, (ta.w & w3) ? 0.4f : 0.5f);
        const float c4 = elem_loss(xb.x, tb.x, (tb.x & w4) ? 0.4f : 0.5f);
        const float c5 = elem_loss(xb.y, tb.y, (tb.y & w5) ? 0.4f : 0.5f);
        const float c6 = elem_loss(xb.z, tb.z, (tb.z & w6) ? 0.4f : 0.5f);
        const float c7 = elem_loss(xb.w, tb.w, (tb.w & w7) ? 0.4f : 0.5f);

        sum += ((c0 + c1) + (c2 + c3)) + ((c4 + c5) + (c6 + c7));
    }

    // scalar tail for n not divisible by 8
    for (int g = 8 * n8 + tid; g < n; g += stride) {
        const int t = tg[g];
        int any = 0;
        #pragma unroll
        for (int k = 1; k <= 5; ++k) if (g - k >= 0) any |= tg[g - k];
        sum += elem_loss(x[g], t, (t & (any ? 1 : 0)) ? 0.4f : 0.5f);
    }

    // wave (64-lane) shfl reduction, then LDS across 4 waves
    #pragma unroll
    for (int off = 32; off > 0; off >>= 1) sum += __shfl_down(sum, off);
    __shared__ float wsum[4];
    const int lane = threadIdx.x & 63;
    const int wid  = threadIdx.x >> 6;
    if (lane == 0) wsum[wid] = sum;
    __syncthreads();
    if (threadIdx.x == 0)
        partial[blockIdx.x] = (wsum[0] + wsum[1]) + (wsum[2] + wsum[3]);
}

__global__ __launch_bounds__(256) void final_reduce_kernel(
        const float* __restrict__ partial, int nb,
        float* __restrict__ out, float invN) {
    float s = 0.0f;
    for (int i = threadIdx.x; i < nb; i += 256) s += partial[i];
    #pragma unroll
    for (int off = 32; off > 0; off >>= 1) s += __shfl_down(s, off);
    __shared__ float wsum[4];
    const int lane = threadIdx.x & 63;
    const int wid  = threadIdx.x >> 6;
    if (lane == 0) wsum[wid] = s;
    __syncthreads();
    if (threadIdx.x == 0)
        out[0] = ((wsum[0] + wsum[1]) + (wsum[2] + wsum[3])) * invN;
}

extern "C" void kernel_launch(void* const* d_in, const int* in_sizes, int n_in,
                              void* d_out, int out_size, void* d_ws, size_t ws_size,
                              hipStream_t stream) {
    const float* x  = (const float*)d_in[0];
    const int*   tg = (const int*)d_in[1];
    float* out      = (float*)d_out;
    float* partial  = (float*)d_ws;

    const int n  = in_sizes[0];
    const int n8 = n / 8;
    const int NB = 2048;   // 8 wg/CU = 32 waves/CU; grid-stride the rest

    loss_partial_kernel<<<NB, 256, 0, stream>>>(x, tg, partial, n8, n);
    final_reduce_kernel<<<1, 256, 0, stream>>>(partial, NB, out, 1.0f / (float)n);
}